// Round 1
// baseline (940.640 us; speedup 1.0000x reference)
//
#include <hip/hip_runtime.h>
#include <math.h>

// Problem constants (match reference)
constexpr int R_ = 8;
constexpr int B_ = 16;
constexpr int D_ = 32;
constexpr int H_ = 128;
constexpr int N_ = 2048;
constexpr int F_ = 256;
constexpr int O_ = 64;               // 2*D
constexpr float HALF_LOG_2PI_ = 0.9189385332046727f;

constexpr int NT = 64;               // rows of N per block
constexpr int NCHUNK = N_ / NT;      // 32

// ---- Kernel 1: elementwise premask W*M into workspace -----------------------
__global__ void mask_mul4(const float4* __restrict__ Wp, const float4* __restrict__ Mp,
                          float4* __restrict__ Op, int n4) {
    int i = blockIdx.x * blockDim.x + threadIdx.x;
    if (i < n4) {
        float4 w = Wp[i], m = Mp[i];
        Op[i] = make_float4(w.x * m.x, w.y * m.y, w.z * m.z, w.w * m.w);
    }
}

// ---- Kernel 2: fused MADE forward + MAF inverse log-prob --------------------
// Block = 256 threads (4 waves). Each block: one (r,b) network, NT=64 rows.
// lane (0..63) = row within tile; g = t/64 (0..3) = output-feature group.
// LDS: xr[64][33], h1[64][129], h2[64][129]  -> padded strides give
// bank = (row + col) % 32 => only 2-way aliasing (free on gfx950).
template<bool PRE>
__global__ __launch_bounds__(256, 2)
void flow_fwd(const float* __restrict__ x,
              const float* __restrict__ W1, const float* __restrict__ W2,
              const float* __restrict__ W3,
              const float* __restrict__ M1, const float* __restrict__ M2,
              const float* __restrict__ M3,
              const int* __restrict__ ridx,
              const float* __restrict__ Wm1, const float* __restrict__ Wm2,
              const float* __restrict__ Wm3,
              float* __restrict__ out)
{
    __shared__ float xr [NT][D_ + 1];    // 64 x 33
    __shared__ float h1s[NT][H_ + 1];    // 64 x 129
    __shared__ float h2s[NT][H_ + 1];    // 64 x 129
    __shared__ float part[4][NT];

    const int bid   = blockIdx.x;
    const int chunk = bid & (NCHUNK - 1);
    const int rb    = bid >> 5;          // 0..127 (NCHUNK==32)
    const int r     = rb >> 4;
    const int n0    = chunk * NT;

    const int t    = threadIdx.x;
    const int lane = t & 63;
    const int g    = t >> 6;

    // ---- stage x tile (gather via region_idx) ----
    {
        int d    = t & 31;
        int nrow = t >> 5;               // 0..7
        int col  = ridx[r * D_ + d];
        for (int i = 0; i < NT; i += 8) {
            int n = nrow + i;
            xr[n][d] = x[(size_t)(n0 + n) * F_ + col];
        }
    }
    __syncthreads();

    // ---- GEMM1: h1 = relu(xr @ W1m)  [64x32]x[32x128] ----
    {
        const int h0 = g * 32;
        float acc[32];
#pragma unroll
        for (int j = 0; j < 32; ++j) acc[j] = 0.f;
        const size_t base1 = (size_t)rb * D_ * H_;
        for (int d = 0; d < D_; ++d) {
            float xv = xr[lane][d];
            const size_t rowb = base1 + (size_t)d * H_ + h0;
#pragma unroll
            for (int j = 0; j < 32; ++j) {
                float w = PRE ? Wm1[rowb + j] : W1[rowb + j] * M1[rowb + j];
                acc[j] = fmaf(xv, w, acc[j]);
            }
        }
#pragma unroll
        for (int j = 0; j < 32; ++j) h1s[lane][h0 + j] = fmaxf(acc[j], 0.f);
    }
    __syncthreads();

    // ---- GEMM2: h2 = relu(h1 @ W2m)  [64x128]x[128x128] ----
    {
        const int k0 = g * 32;
        float acc[32];
#pragma unroll
        for (int j = 0; j < 32; ++j) acc[j] = 0.f;
        const size_t base2 = (size_t)rb * H_ * H_;
        for (int h = 0; h < H_; ++h) {
            float hv = h1s[lane][h];
            const size_t rowb = base2 + (size_t)h * H_ + k0;
#pragma unroll
            for (int j = 0; j < 32; ++j) {
                float w = PRE ? Wm2[rowb + j] : W2[rowb + j] * M2[rowb + j];
                acc[j] = fmaf(hv, w, acc[j]);
            }
        }
#pragma unroll
        for (int j = 0; j < 32; ++j) h2s[lane][k0 + j] = fmaxf(acc[j], 0.f);
    }
    __syncthreads();

    // ---- GEMM3 + MAF epilogue: out = h2 @ W3m  [64x128]x[128x64] ----
    {
        const int o0 = g * 16;           // 16 outputs = 8 (shift,log_scale) pairs
        float acc[16];
#pragma unroll
        for (int j = 0; j < 16; ++j) acc[j] = 0.f;
        const size_t base3 = (size_t)rb * H_ * O_;
        for (int h = 0; h < H_; ++h) {
            float hv = h2s[lane][h];
            const size_t rowb = base3 + (size_t)h * O_ + o0;
#pragma unroll
            for (int j = 0; j < 16; ++j) {
                float w = PRE ? Wm3[rowb + j] : W3[rowb + j] * M3[rowb + j];
                acc[j] = fmaf(hv, w, acc[j]);
            }
        }
        float ll = 0.f;
#pragma unroll
        for (int j = 0; j < 8; ++j) {
            int   dl    = g * 8 + j;     // global d index for this pair
            float shift = acc[2 * j];
            float ls    = acc[2 * j + 1];
            float xv    = xr[lane][dl];
            float u     = (xv - shift) * expf(-ls);
            ll += fmaf(-0.5f * u, u, -HALF_LOG_2PI_ - ls);
        }
        part[g][lane] = ll;
    }
    __syncthreads();

    // ---- reduce the 4 groups, write out[n, r, b] ----
    if (t < NT) {
        float ll = part[0][t] + part[1][t] + part[2][t] + part[3][t];
        const int b = rb & 15;
        out[(size_t)(n0 + t) * (R_ * B_) + r * B_ + b] = ll;
    }
}

extern "C" void kernel_launch(void* const* d_in, const int* in_sizes, int n_in,
                              void* d_out, int out_size, void* d_ws, size_t ws_size,
                              hipStream_t stream) {
    const float* x   = (const float*)d_in[0];
    const float* W1  = (const float*)d_in[1];
    const float* W2  = (const float*)d_in[2];
    const float* W3  = (const float*)d_in[3];
    const float* M1  = (const float*)d_in[4];
    const float* M2  = (const float*)d_in[5];
    const float* M3  = (const float*)d_in[6];
    const int*  ridx = (const int*)d_in[7];
    float* out = (float*)d_out;

    const size_t n1 = (size_t)R_ * B_ * D_ * H_;   //  524288
    const size_t n2 = (size_t)R_ * B_ * H_ * H_;   // 2097152
    const size_t n3 = (size_t)R_ * B_ * H_ * O_;   // 1048576
    const size_t need = (n1 + n2 + n3) * sizeof(float);

    const bool pre = (d_ws != nullptr) && (ws_size >= need);

    float* Wm1 = (float*)d_ws;
    float* Wm2 = Wm1 + n1;
    float* Wm3 = Wm2 + n2;

    dim3 blk(256);
    dim3 grd(R_ * B_ * NCHUNK);

    if (pre) {
        mask_mul4<<<dim3((unsigned)(n1 / 4 / 256)), blk, 0, stream>>>(
            (const float4*)W1, (const float4*)M1, (float4*)Wm1, (int)(n1 / 4));
        mask_mul4<<<dim3((unsigned)(n2 / 4 / 256)), blk, 0, stream>>>(
            (const float4*)W2, (const float4*)M2, (float4*)Wm2, (int)(n2 / 4));
        mask_mul4<<<dim3((unsigned)(n3 / 4 / 256)), blk, 0, stream>>>(
            (const float4*)W3, (const float4*)M3, (float4*)Wm3, (int)(n3 / 4));
        flow_fwd<true><<<grd, blk, 0, stream>>>(x, W1, W2, W3, M1, M2, M3, ridx,
                                                Wm1, Wm2, Wm3, out);
    } else {
        flow_fwd<false><<<grd, blk, 0, stream>>>(x, W1, W2, W3, M1, M2, M3, ridx,
                                                 nullptr, nullptr, nullptr, out);
    }
}

// Round 2
// 324.144 us; speedup vs baseline: 2.9019x; 2.9019x over previous
//
#include <hip/hip_runtime.h>
#include <math.h>

// Problem constants (match reference)
constexpr int R_ = 8;
constexpr int B_ = 16;
constexpr int D_ = 32;
constexpr int H_ = 128;
constexpr int N_ = 2048;
constexpr int F_ = 256;
constexpr int O_ = 64;               // 2*D
constexpr float HLP_ = 0.9189385332046727f;

constexpr int NT  = 128;             // rows of N per block
constexpr int NB  = N_ / NT;         // 16 chunks
constexpr int NTH = 512;             // threads per block (8 waves)

// ---- Kernel 1: fused elementwise premask W*M for all three layers ----------
__global__ void mask_all(const float4* __restrict__ W1, const float4* __restrict__ M1, float4* __restrict__ O1,
                         const float4* __restrict__ W2, const float4* __restrict__ M2, float4* __restrict__ O2,
                         const float4* __restrict__ W3, const float4* __restrict__ M3, float4* __restrict__ O3) {
    constexpr int n1 = R_ * B_ * D_ * H_ / 4;   // 131072
    constexpr int n2 = R_ * B_ * H_ * H_ / 4;   // 524288
    constexpr int n3 = R_ * B_ * H_ * O_ / 4;   // 262144
    int i = blockIdx.x * blockDim.x + threadIdx.x;
    if (i < n1) {
        float4 w = W1[i], m = M1[i];
        O1[i] = make_float4(w.x * m.x, w.y * m.y, w.z * m.z, w.w * m.w);
    } else if (i < n1 + n2) {
        int j = i - n1;
        float4 w = W2[j], m = M2[j];
        O2[j] = make_float4(w.x * m.x, w.y * m.y, w.z * m.z, w.w * m.w);
    } else if (i < n1 + n2 + n3) {
        int j = i - n1 - n2;
        float4 w = W3[j], m = M3[j];
        O3[j] = make_float4(w.x * m.x, w.y * m.y, w.z * m.z, w.w * m.w);
    }
}

// ---- Kernel 2: fused MADE forward + MAF inverse log-prob --------------------
// Block = 512 threads (8 waves, 2/SIMD), one (r,b) network, NT=128 rows.
// Register tiling: thread (tr=t/16, tc=t%16) owns rows tr*4..+4 and cols
// tc*8..+8 (GEMM1/2) or tc*4..+4 (GEMM3).
// Activations live TRANSPOSED in LDS: hT[k][row] -> A-fragment reads are
// ds_read_b128 at addr k*128 + tr*4, 32 distinct words across the wave's
// 4 tr-groups => conflict-free. Weights are read straight from L2 with
// coalesced dwordx4 (16 tc-groups * 32B = 512B contiguous per wave).
template<bool PRE>
__global__ __launch_bounds__(NTH, 2)
void flow_fwd(const float* __restrict__ x,
              const float* __restrict__ W1, const float* __restrict__ W2,
              const float* __restrict__ W3,
              const float* __restrict__ M1, const float* __restrict__ M2,
              const float* __restrict__ M3,
              const int* __restrict__ ridx,
              const float* __restrict__ Wm1, const float* __restrict__ Wm2,
              const float* __restrict__ Wm3,
              float* __restrict__ out)
{
    __shared__ float xT [D_][NT + 4];   // [d][row], pad 132 -> 4-way max on gather writes
    __shared__ float h1T[H_][NT];       // [k][row]
    __shared__ float h2T[H_][NT];       // [k][row]
    __shared__ float part[16][NT + 4];  // [tc][row] partial log-probs
    // total LDS: 16896 + 65536 + 65536 + 8448 = 156416 B (1 block/CU)

    const int bid   = blockIdx.x;
    const int rb    = bid >> 4;          // 0..127  (network)
    const int r     = rb >> 4;
    const int chunk = bid & (NB - 1);
    const int n0    = chunk * NT;

    const int t   = threadIdx.x;
    const int tr  = t >> 4;              // 0..31
    const int tc  = t & 15;              // 0..15
    const int tr4 = tr * 4;
    const int tc8 = tc * 8;
    const int tc4 = tc * 4;

    // ---- stage x tile, transposed: xT[d][row] ----
    {
        int d  = t & 31;
        int rg = t >> 5;                 // 0..15
        int col = ridx[r * D_ + d];
        const float* xp = x + (size_t)(n0 + rg * 8) * F_ + col;
#pragma unroll
        for (int i = 0; i < 8; ++i)
            xT[d][rg * 8 + i] = xp[i * F_];
    }
    __syncthreads();

    // ---- GEMM1: h1T[c][row] = relu(sum_d xT[d][row] * W1m[d][c])  K=32, 4x8 tile
    {
        float acc[4][8];
#pragma unroll
        for (int i = 0; i < 4; ++i)
#pragma unroll
            for (int j = 0; j < 8; ++j) acc[i][j] = 0.f;
        const float* Wb = (PRE ? Wm1 : W1) + (size_t)rb * D_ * H_;
        const float* Mb = M1 + (size_t)rb * D_ * H_;
        for (int k0 = 0; k0 < D_; k0 += 4) {
            float a[4][4], b[4][8];
#pragma unroll
            for (int kk = 0; kk < 4; ++kk)
                *(float4*)&a[kk][0] = *(const float4*)&xT[k0 + kk][tr4];
#pragma unroll
            for (int kk = 0; kk < 4; ++kk) {
                const float* wr = Wb + (k0 + kk) * H_ + tc8;
                *(float4*)&b[kk][0] = *(const float4*)(wr);
                *(float4*)&b[kk][4] = *(const float4*)(wr + 4);
                if (!PRE) {
                    const float* mr = Mb + (k0 + kk) * H_ + tc8;
                    float4 m0 = *(const float4*)(mr), m1 = *(const float4*)(mr + 4);
                    b[kk][0] *= m0.x; b[kk][1] *= m0.y; b[kk][2] *= m0.z; b[kk][3] *= m0.w;
                    b[kk][4] *= m1.x; b[kk][5] *= m1.y; b[kk][6] *= m1.z; b[kk][7] *= m1.w;
                }
            }
#pragma unroll
            for (int kk = 0; kk < 4; ++kk)
#pragma unroll
                for (int i = 0; i < 4; ++i)
#pragma unroll
                    for (int j = 0; j < 8; ++j)
                        acc[i][j] = fmaf(a[kk][i], b[kk][j], acc[i][j]);
        }
#pragma unroll
        for (int j = 0; j < 8; ++j) {
            float4 v = make_float4(fmaxf(acc[0][j], 0.f), fmaxf(acc[1][j], 0.f),
                                   fmaxf(acc[2][j], 0.f), fmaxf(acc[3][j], 0.f));
            *(float4*)&h1T[tc8 + j][tr4] = v;
        }
    }
    __syncthreads();

    // ---- GEMM2: h2T = relu(h1 @ W2m)  K=128, 4x8 tile ----
    {
        float acc[4][8];
#pragma unroll
        for (int i = 0; i < 4; ++i)
#pragma unroll
            for (int j = 0; j < 8; ++j) acc[i][j] = 0.f;
        const float* Wb = (PRE ? Wm2 : W2) + (size_t)rb * H_ * H_;
        const float* Mb = M2 + (size_t)rb * H_ * H_;
        for (int k0 = 0; k0 < H_; k0 += 4) {
            float a[4][4], b[4][8];
#pragma unroll
            for (int kk = 0; kk < 4; ++kk)
                *(float4*)&a[kk][0] = *(const float4*)&h1T[k0 + kk][tr4];
#pragma unroll
            for (int kk = 0; kk < 4; ++kk) {
                const float* wr = Wb + (k0 + kk) * H_ + tc8;
                *(float4*)&b[kk][0] = *(const float4*)(wr);
                *(float4*)&b[kk][4] = *(const float4*)(wr + 4);
                if (!PRE) {
                    const float* mr = Mb + (k0 + kk) * H_ + tc8;
                    float4 m0 = *(const float4*)(mr), m1 = *(const float4*)(mr + 4);
                    b[kk][0] *= m0.x; b[kk][1] *= m0.y; b[kk][2] *= m0.z; b[kk][3] *= m0.w;
                    b[kk][4] *= m1.x; b[kk][5] *= m1.y; b[kk][6] *= m1.z; b[kk][7] *= m1.w;
                }
            }
#pragma unroll
            for (int kk = 0; kk < 4; ++kk)
#pragma unroll
                for (int i = 0; i < 4; ++i)
#pragma unroll
                    for (int j = 0; j < 8; ++j)
                        acc[i][j] = fmaf(a[kk][i], b[kk][j], acc[i][j]);
        }
#pragma unroll
        for (int j = 0; j < 8; ++j) {
            float4 v = make_float4(fmaxf(acc[0][j], 0.f), fmaxf(acc[1][j], 0.f),
                                   fmaxf(acc[2][j], 0.f), fmaxf(acc[3][j], 0.f));
            *(float4*)&h2T[tc8 + j][tr4] = v;
        }
    }
    __syncthreads();

    // ---- GEMM3 + MAF epilogue: K=128, 4x4 tile (cols tc*4.. = 2 (shift,ls) pairs)
    {
        float acc[4][4];
#pragma unroll
        for (int i = 0; i < 4; ++i)
#pragma unroll
            for (int j = 0; j < 4; ++j) acc[i][j] = 0.f;
        const float* Wb = (PRE ? Wm3 : W3) + (size_t)rb * H_ * O_;
        const float* Mb = M3 + (size_t)rb * H_ * O_;
        for (int k0 = 0; k0 < H_; k0 += 4) {
            float a[4][4], b[4][4];
#pragma unroll
            for (int kk = 0; kk < 4; ++kk)
                *(float4*)&a[kk][0] = *(const float4*)&h2T[k0 + kk][tr4];
#pragma unroll
            for (int kk = 0; kk < 4; ++kk) {
                const float* wr = Wb + (k0 + kk) * O_ + tc4;
                *(float4*)&b[kk][0] = *(const float4*)(wr);
                if (!PRE) {
                    const float* mr = Mb + (k0 + kk) * O_ + tc4;
                    float4 m0 = *(const float4*)(mr);
                    b[kk][0] *= m0.x; b[kk][1] *= m0.y; b[kk][2] *= m0.z; b[kk][3] *= m0.w;
                }
            }
#pragma unroll
            for (int kk = 0; kk < 4; ++kk)
#pragma unroll
                for (int i = 0; i < 4; ++i)
#pragma unroll
                    for (int j = 0; j < 4; ++j)
                        acc[i][j] = fmaf(a[kk][i], b[kk][j], acc[i][j]);
        }
        // epilogue: cols tc*4+{0,1,2,3} = (shift,ls) for d=2*tc and d=2*tc+1
#pragma unroll
        for (int i = 0; i < 4; ++i) {
            int row = tr4 + i;
            float ll = 0.f;
#pragma unroll
            for (int q = 0; q < 2; ++q) {
                float shift = acc[i][2 * q];
                float ls    = acc[i][2 * q + 1];
                float xv    = xT[2 * tc + q][row];
                float u     = (xv - shift) * __expf(-ls);
                ll = fmaf(-0.5f * u, u, ll - HLP_ - ls);
            }
            part[tc][row] = ll;
        }
    }
    __syncthreads();

    // ---- reduce over the 16 tc-groups, write out[n, rb] ----
    if (t < NT) {
        float s = 0.f;
#pragma unroll
        for (int c = 0; c < 16; ++c) s += part[c][t];
        out[(size_t)(n0 + t) * (R_ * B_) + rb] = s;
    }
}

extern "C" void kernel_launch(void* const* d_in, const int* in_sizes, int n_in,
                              void* d_out, int out_size, void* d_ws, size_t ws_size,
                              hipStream_t stream) {
    const float* x   = (const float*)d_in[0];
    const float* W1  = (const float*)d_in[1];
    const float* W2  = (const float*)d_in[2];
    const float* W3  = (const float*)d_in[3];
    const float* M1  = (const float*)d_in[4];
    const float* M2  = (const float*)d_in[5];
    const float* M3  = (const float*)d_in[6];
    const int*  ridx = (const int*)d_in[7];
    float* out = (float*)d_out;

    const size_t n1 = (size_t)R_ * B_ * D_ * H_;   //  524288
    const size_t n2 = (size_t)R_ * B_ * H_ * H_;   // 2097152
    const size_t n3 = (size_t)R_ * B_ * H_ * O_;   // 1048576
    const size_t need = (n1 + n2 + n3) * sizeof(float);

    const bool pre = (d_ws != nullptr) && (ws_size >= need);

    float* Wm1 = (float*)d_ws;
    float* Wm2 = Wm1 + n1;
    float* Wm3 = Wm2 + n2;

    dim3 grd(R_ * B_ * NB);    // 2048 blocks
    dim3 blk(NTH);

    if (pre) {
        const int tot4 = (int)((n1 + n2 + n3) / 4);   // 917504
        mask_all<<<dim3((tot4 + 255) / 256), dim3(256), 0, stream>>>(
            (const float4*)W1, (const float4*)M1, (float4*)Wm1,
            (const float4*)W2, (const float4*)M2, (float4*)Wm2,
            (const float4*)W3, (const float4*)M3, (float4*)Wm3);
        flow_fwd<true><<<grd, blk, 0, stream>>>(x, W1, W2, W3, M1, M2, M3, ridx,
                                                Wm1, Wm2, Wm3, out);
    } else {
        flow_fwd<false><<<grd, blk, 0, stream>>>(x, W1, W2, W3, M1, M2, M3, ridx,
                                                 nullptr, nullptr, nullptr, out);
    }
}

// Round 3
// 133.009 us; speedup vs baseline: 7.0720x; 2.4370x over previous
//
#include <hip/hip_runtime.h>
#include <math.h>

// Problem constants
constexpr int R_ = 8;
constexpr int B_ = 16;
constexpr int D_ = 32;
constexpr int H_ = 128;
constexpr int N_ = 2048;
constexpr int F_ = 256;
constexpr int O_ = 64;               // 2*D
constexpr float HLP_ = 0.9189385332046727f;

typedef float f32x4 __attribute__((ext_vector_type(4)));
typedef short bf16x8 __attribute__((ext_vector_type(8)));

__device__ __forceinline__ unsigned short f2bf(float f) {
    unsigned u = __builtin_bit_cast(unsigned, f);
    unsigned r = (u + 0x7FFFu + ((u >> 16) & 1u)) >> 16;
    return (unsigned short)r;
}

// XOR slot swizzle for LDS fragment arrays: spreads C-layout b16 writes
// across banks while keeping b128 fragment reads full-rate (any 8
// consecutive lanes stay distinct mod 8).
__device__ __forceinline__ int sl(int l) { return l ^ ((l >> 3) & 6); }

// ---------------------------------------------------------------------------
// Pack kernel: Wl*Ml -> bf16, stored in MFMA B-fragment order.
// frag layout: [fragid][lane][j] ; B[k][n]: n = nt*16 + (lane&15),
//                                  k = kt*32 + ((lane>>4)&3)*8 + j
// Per network: L1 has 8 frags (kt=0, nt 0..7), L2 32 (kt 0..3, nt 0..7),
// L3 16 (kt 0..3, nt 0..3). 56 frags/network, 7168 total.
// ---------------------------------------------------------------------------
__global__ void pack_w(const float* __restrict__ W1, const float* __restrict__ M1,
                       const float* __restrict__ W2, const float* __restrict__ M2,
                       const float* __restrict__ W3, const float* __restrict__ M3,
                       unsigned short* __restrict__ P1, unsigned short* __restrict__ P2,
                       unsigned short* __restrict__ P3) {
    int gid  = blockIdx.x * blockDim.x + threadIdx.x;
    int lane = gid & 63;
    int frag = gid >> 6;
    if (frag >= 128 * 56) return;
    int rb  = frag / 56;
    int rem = frag - rb * 56;
    const float *W, *M;
    unsigned short* P;
    int K, Nn, kt, nt, fi;
    if (rem < 8)       { W = W1; M = M1; P = P1; K = 32;  Nn = 128; kt = 0;      nt = rem;   fi = rb * 8  + rem; }
    else if (rem < 40) { int q = rem - 8;  W = W2; M = M2; P = P2; K = 128; Nn = 128; kt = q >> 3; nt = q & 7; fi = rb * 32 + q; }
    else               { int q = rem - 40; W = W3; M = M3; P = P3; K = 128; Nn = 64;  kt = q >> 2; nt = q & 3; fi = rb * 16 + q; }
    int n  = nt * 16 + (lane & 15);
    int k0 = kt * 32 + ((lane >> 4) & 3) * 8;
    size_t src = (size_t)rb * K * Nn + (size_t)k0 * Nn + n;
    unsigned short v[8];
#pragma unroll
    for (int j = 0; j < 8; ++j)
        v[j] = f2bf(W[src + (size_t)j * Nn] * M[src + (size_t)j * Nn]);
    *(bf16x8*)(P + ((size_t)fi * 64 + lane) * 8) = *(bf16x8*)v;
}

// ---------------------------------------------------------------------------
// Main kernel: 2048 blocks = 128 networks x 16 row-chunks (128 rows each).
// 512 threads = 8 waves; wave w: wm = w&1 (row half), wn = w>>1 (col quarter).
// GEMM1/2: wave owns mt in [wm*4, wm*4+4), nt in {wn*2, wn*2+1}.
// GEMM3:   wave owns same mt range, nt3 = wn.
// Activations in LDS as packed A-frags [mt][kt][slot][8] bf16.
// ---------------------------------------------------------------------------
__global__ __launch_bounds__(512, 4)
void flow_mfma(const float* __restrict__ x, const int* __restrict__ ridx,
               const unsigned short* __restrict__ P1,
               const unsigned short* __restrict__ P2,
               const unsigned short* __restrict__ P3,
               float* __restrict__ out)
{
    __shared__ __align__(16) unsigned short xbp[8 * 64 * 8];        //  8 KB [mt][slot][j]
    __shared__ __align__(16) unsigned short h1p[8 * 4 * 64 * 8];    // 32 KB [mt][kt][slot][j]
    __shared__ __align__(16) unsigned short h2p[8 * 4 * 64 * 8];    // 32 KB
    __shared__ float part[4][132];                                  // ~2 KB [wn][row]

    const int bid   = blockIdx.x;
    const int rb    = bid >> 4;
    const int chunk = bid & 15;
    const int n0    = chunk * 128;
    const int r     = rb >> 4;

    const int t    = threadIdx.x;
    const int lane = t & 63;
    const int w    = t >> 6;
    const int wm   = w & 1;
    const int wn   = w >> 1;
    const int q    = lane >> 4;
    const int c    = lane & 15;

    // ---- gather x -> bf16 A-frags (one thread per (row, d-octet)) ----
    {
        int row = t >> 2;            // 0..127
        int dq  = t & 3;             // 0..3
        const int* rp = ridx + r * 32 + dq * 8;
        const float* xrow = x + (size_t)(n0 + row) * F_;
        unsigned short v[8];
#pragma unroll
        for (int j = 0; j < 8; ++j) v[j] = f2bf(xrow[rp[j]]);
        int mt = row >> 4;
        int lx = (row & 15) | (dq << 4);
        *(bf16x8*)&xbp[((mt * 64) + sl(lx)) * 8] = *(bf16x8*)v;
    }
    __syncthreads();

    // ---- GEMM1: h1 = relu(x @ W1m)  K=32 (one MFMA per tile) ----
    {
        f32x4 acc1[4][2];
        bf16x8 af[4], bf_[2];
#pragma unroll
        for (int i = 0; i < 4; ++i) {
            int mt = wm * 4 + i;
            af[i] = *(bf16x8*)&xbp[(mt * 64 + sl(lane)) * 8];
        }
#pragma unroll
        for (int jn = 0; jn < 2; ++jn) {
            int nt = wn * 2 + jn;
            bf_[jn] = *(const bf16x8*)(P1 + ((size_t)(rb * 8 + nt) * 64 + lane) * 8);
        }
        f32x4 z = {0.f, 0.f, 0.f, 0.f};
#pragma unroll
        for (int i = 0; i < 4; ++i)
#pragma unroll
            for (int jn = 0; jn < 2; ++jn)
                acc1[i][jn] = __builtin_amdgcn_mfma_f32_16x16x32_bf16(af[i], bf_[jn], z, 0, 0, 0);
        // store C-layout -> packed A-frag LDS (relu + bf16)
#pragma unroll
        for (int i = 0; i < 4; ++i) {
            int mt = wm * 4 + i;
#pragma unroll
            for (int jn = 0; jn < 2; ++jn) {
                int ntc   = wn * 2 + jn;
                int col   = ntc * 16 + c;
                int kt2   = col >> 5;
                int quad2 = (col >> 3) & 3;
                int j     = col & 7;
#pragma unroll
                for (int rg = 0; rg < 4; ++rg) {
                    float v = fmaxf(acc1[i][jn][rg], 0.f);
                    int l2 = (q * 4 + rg) | (quad2 << 4);
                    h1p[((mt * 4 + kt2) * 64 + sl(l2)) * 8 + j] = f2bf(v);
                }
            }
        }
    }
    __syncthreads();

    // ---- GEMM2: h2 = relu(h1 @ W2m)  K=128 ----
    {
        f32x4 acc2[4][2];
#pragma unroll
        for (int i = 0; i < 4; ++i)
#pragma unroll
            for (int jn = 0; jn < 2; ++jn) acc2[i][jn] = (f32x4){0.f, 0.f, 0.f, 0.f};
#pragma unroll
        for (int kt = 0; kt < 4; ++kt) {
            bf16x8 bfr[2];
#pragma unroll
            for (int jn = 0; jn < 2; ++jn) {
                int nt = wn * 2 + jn;
                bfr[jn] = *(const bf16x8*)(P2 + ((size_t)(rb * 32 + kt * 8 + nt) * 64 + lane) * 8);
            }
#pragma unroll
            for (int i = 0; i < 4; ++i) {
                int mt = wm * 4 + i;
                bf16x8 a = *(bf16x8*)&h1p[((mt * 4 + kt) * 64 + sl(lane)) * 8];
#pragma unroll
                for (int jn = 0; jn < 2; ++jn)
                    acc2[i][jn] = __builtin_amdgcn_mfma_f32_16x16x32_bf16(a, bfr[jn], acc2[i][jn], 0, 0, 0);
            }
        }
#pragma unroll
        for (int i = 0; i < 4; ++i) {
            int mt = wm * 4 + i;
#pragma unroll
            for (int jn = 0; jn < 2; ++jn) {
                int ntc   = wn * 2 + jn;
                int col   = ntc * 16 + c;
                int kt2   = col >> 5;
                int quad2 = (col >> 3) & 3;
                int j     = col & 7;
#pragma unroll
                for (int rg = 0; rg < 4; ++rg) {
                    float v = fmaxf(acc2[i][jn][rg], 0.f);
                    int l2 = (q * 4 + rg) | (quad2 << 4);
                    h2p[((mt * 4 + kt2) * 64 + sl(l2)) * 8 + j] = f2bf(v);
                }
            }
        }
    }
    __syncthreads();

    // ---- GEMM3 + MAF epilogue: out = h2 @ W3m  (N=64, wave's nt3 = wn) ----
    {
        f32x4 acc3[4];
#pragma unroll
        for (int i = 0; i < 4; ++i) acc3[i] = (f32x4){0.f, 0.f, 0.f, 0.f};
#pragma unroll
        for (int kt = 0; kt < 4; ++kt) {
            bf16x8 b = *(const bf16x8*)(P3 + ((size_t)(rb * 16 + kt * 4 + wn) * 64 + lane) * 8);
#pragma unroll
            for (int i = 0; i < 4; ++i) {
                int mt = wm * 4 + i;
                bf16x8 a = *(bf16x8*)&h2p[((mt * 4 + kt) * 64 + sl(lane)) * 8];
                acc3[i] = __builtin_amdgcn_mfma_f32_16x16x32_bf16(a, b, acc3[i], 0, 0, 0);
            }
        }
        // col = wn*16 + c = 2*d + p  ->  d = wn*8 + (c>>1), p = c&1 (0=shift,1=ls)
        const int d    = wn * 8 + (c >> 1);
        const int colx = ridx[r * 32 + d];
        // even-c lanes handle regs {0,1}; odd-c regs {2,3}
        float xv[4][2];
#pragma unroll
        for (int i = 0; i < 4; ++i)
#pragma unroll
            for (int rr = 0; rr < 2; ++rr) {
                int rg  = (c & 1) * 2 + rr;
                int row = (wm * 4 + i) * 16 + q * 4 + rg;
                xv[i][rr] = x[(size_t)(n0 + row) * F_ + colx];
            }
        float ps[4][2];
#pragma unroll
        for (int i = 0; i < 4; ++i) {
            float oth[4];
#pragma unroll
            for (int rg = 0; rg < 4; ++rg) oth[rg] = __shfl_xor(acc3[i][rg], 1, 64);
#pragma unroll
            for (int rr = 0; rr < 2; ++rr) {
                int rg = (c & 1) * 2 + rr;
                float shift = (c & 1) ? oth[rg]     : acc3[i][rg];
                float ls    = (c & 1) ? acc3[i][rg] : oth[rg];
                float u = (xv[i][rr] - shift) * __expf(-ls);
                ps[i][rr] = fmaf(-0.5f * u, u, -HLP_ - ls);
            }
        }
        // reduce over the 8 d-values held across c>>1 (lane bits 1..3)
#pragma unroll
        for (int m = 2; m <= 8; m <<= 1)
#pragma unroll
            for (int i = 0; i < 4; ++i) {
                ps[i][0] += __shfl_xor(ps[i][0], m, 64);
                ps[i][1] += __shfl_xor(ps[i][1], m, 64);
            }
        if ((c >> 1) == 0) {             // c in {0,1}
#pragma unroll
            for (int i = 0; i < 4; ++i)
#pragma unroll
                for (int rr = 0; rr < 2; ++rr) {
                    int rg  = (c & 1) * 2 + rr;
                    int row = (wm * 4 + i) * 16 + q * 4 + rg;
                    part[wn][row] = ps[i][rr];
                }
        }
    }
    __syncthreads();

    if (t < 128) {
        float s = part[0][t] + part[1][t] + part[2][t] + part[3][t];
        out[(size_t)(n0 + t) * (R_ * B_) + rb] = s;
    }
}

// ---------------------------------------------------------------------------
// Fallback (ws too small): round-2 fp32 kernel, masks applied on the fly.
// ---------------------------------------------------------------------------
__global__ __launch_bounds__(512, 2)
void flow_fb(const float* __restrict__ x,
             const float* __restrict__ W1, const float* __restrict__ W2,
             const float* __restrict__ W3,
             const float* __restrict__ M1, const float* __restrict__ M2,
             const float* __restrict__ M3,
             const int* __restrict__ ridx, float* __restrict__ out)
{
    __shared__ float xT[D_][132];
    __shared__ float h1T[H_][128];
    __shared__ float h2T[H_][128];
    __shared__ float part[16][132];
    const int bid = blockIdx.x, rb = bid >> 4, r = rb >> 4;
    const int n0 = (bid & 15) * 128;
    const int t = threadIdx.x, tr = t >> 4, tc = t & 15;
    const int tr4 = tr * 4, tc8 = tc * 8, tc4 = tc * 4;
    {
        int d = t & 31, rg = t >> 5;
        int col = ridx[r * D_ + d];
        const float* xp = x + (size_t)(n0 + rg * 8) * F_ + col;
#pragma unroll
        for (int i = 0; i < 8; ++i) xT[d][rg * 8 + i] = xp[i * F_];
    }
    __syncthreads();
    {
        float acc[4][8];
#pragma unroll
        for (int i = 0; i < 4; ++i)
#pragma unroll
            for (int j = 0; j < 8; ++j) acc[i][j] = 0.f;
        const float* Wb = W1 + (size_t)rb * D_ * H_;
        const float* Mb = M1 + (size_t)rb * D_ * H_;
        for (int k = 0; k < D_; ++k) {
            float a[4]; *(float4*)a = *(const float4*)&xT[k][tr4];
            const float* wr = Wb + k * H_ + tc8;
            const float* mr = Mb + k * H_ + tc8;
#pragma unroll
            for (int j = 0; j < 8; ++j) {
                float wv = wr[j] * mr[j];
#pragma unroll
                for (int i = 0; i < 4; ++i) acc[i][j] = fmaf(a[i], wv, acc[i][j]);
            }
        }
#pragma unroll
        for (int j = 0; j < 8; ++j) {
            float4 v = make_float4(fmaxf(acc[0][j], 0.f), fmaxf(acc[1][j], 0.f),
                                   fmaxf(acc[2][j], 0.f), fmaxf(acc[3][j], 0.f));
            *(float4*)&h1T[tc8 + j][tr4] = v;
        }
    }
    __syncthreads();
    {
        float acc[4][8];
#pragma unroll
        for (int i = 0; i < 4; ++i)
#pragma unroll
            for (int j = 0; j < 8; ++j) acc[i][j] = 0.f;
        const float* Wb = W2 + (size_t)rb * H_ * H_;
        const float* Mb = M2 + (size_t)rb * H_ * H_;
        for (int k = 0; k < H_; ++k) {
            float a[4]; *(float4*)a = *(const float4*)&h1T[k][tr4];
            const float* wr = Wb + k * H_ + tc8;
            const float* mr = Mb + k * H_ + tc8;
#pragma unroll
            for (int j = 0; j < 8; ++j) {
                float wv = wr[j] * mr[j];
#pragma unroll
                for (int i = 0; i < 4; ++i) acc[i][j] = fmaf(a[i], wv, acc[i][j]);
            }
        }
#pragma unroll
        for (int j = 0; j < 8; ++j) {
            float4 v = make_float4(fmaxf(acc[0][j], 0.f), fmaxf(acc[1][j], 0.f),
                                   fmaxf(acc[2][j], 0.f), fmaxf(acc[3][j], 0.f));
            *(float4*)&h2T[tc8 + j][tr4] = v;
        }
    }
    __syncthreads();
    {
        float acc[4][4];
#pragma unroll
        for (int i = 0; i < 4; ++i)
#pragma unroll
            for (int j = 0; j < 4; ++j) acc[i][j] = 0.f;
        const float* Wb = W3 + (size_t)rb * H_ * O_;
        const float* Mb = M3 + (size_t)rb * H_ * O_;
        for (int k = 0; k < H_; ++k) {
            float a[4]; *(float4*)a = *(const float4*)&h2T[k][tr4];
            const float* wr = Wb + k * O_ + tc4;
            const float* mr = Mb + k * O_ + tc4;
#pragma unroll
            for (int j = 0; j < 4; ++j) {
                float wv = wr[j] * mr[j];
#pragma unroll
                for (int i = 0; i < 4; ++i) acc[i][j] = fmaf(a[i], wv, acc[i][j]);
            }
        }
#pragma unroll
        for (int i = 0; i < 4; ++i) {
            int row = tr4 + i;
            float ll = 0.f;
#pragma unroll
            for (int qd = 0; qd < 2; ++qd) {
                float shift = acc[i][2 * qd], ls = acc[i][2 * qd + 1];
                float xvv = xT[2 * tc + qd][row];
                float u = (xvv - shift) * __expf(-ls);
                ll = fmaf(-0.5f * u, u, ll - HLP_ - ls);
            }
            part[tc][row] = ll;
        }
    }
    __syncthreads();
    if (t < 128) {
        float s = 0.f;
#pragma unroll
        for (int cc = 0; cc < 16; ++cc) s += part[cc][t];
        out[(size_t)(n0 + t) * (R_ * B_) + rb] = s;
    }
}

extern "C" void kernel_launch(void* const* d_in, const int* in_sizes, int n_in,
                              void* d_out, int out_size, void* d_ws, size_t ws_size,
                              hipStream_t stream) {
    const float* x   = (const float*)d_in[0];
    const float* W1  = (const float*)d_in[1];
    const float* W2  = (const float*)d_in[2];
    const float* W3  = (const float*)d_in[3];
    const float* M1  = (const float*)d_in[4];
    const float* M2  = (const float*)d_in[5];
    const float* M3  = (const float*)d_in[6];
    const int*  ridx = (const int*)d_in[7];
    float* out = (float*)d_out;

    const size_t s1 = (size_t)128 * 8  * 512;   // P1 shorts
    const size_t s2 = (size_t)128 * 32 * 512;   // P2 shorts
    const size_t s3 = (size_t)128 * 16 * 512;   // P3 shorts
    const size_t need = (s1 + s2 + s3) * sizeof(unsigned short);   // 7 MB

    if (d_ws != nullptr && ws_size >= need) {
        unsigned short* P1 = (unsigned short*)d_ws;
        unsigned short* P2 = P1 + s1;
        unsigned short* P3 = P2 + s2;
        pack_w<<<dim3(1792), dim3(256), 0, stream>>>(W1, M1, W2, M2, W3, M3, P1, P2, P3);
        flow_mfma<<<dim3(2048), dim3(512), 0, stream>>>(x, ridx, P1, P2, P3, out);
    } else {
        flow_fb<<<dim3(2048), dim3(512), 0, stream>>>(x, W1, W2, W3, M1, M2, M3, ridx, out);
    }
}